// Round 6
// baseline (72.438 us; speedup 1.0000x reference)
//
#include <hip/hip_runtime.h>

// Problem constants (fixed by the reference's setup_inputs, seed 0)
#define IN_F   256
#define N_ASS  4096
#define OUT_F  256
#define BATCH  128
#define ASS0   256      // first associative node index
#define OUT0   4352     // first output node index
#define SPLITK2 32      // gemm2 split-K (K=4096 -> 32 chunks of 128)

// ws layout (float offsets):
//   W1T @ 0   : [IN_F=256][N_ASS=4096]   input->assoc, src-major (4 MB)
//   W2T @ 1M  : [N_ASS=4096][OUT_F=256]  assoc->output, src-major (4 MB)
//   P1  @ 2M  : [2][BATCH=128][N_ASS]    gemm1 split-K partials (4 MB)
//   P2  @ 4M  : [32][BATCH][OUT_F]       gemm2 split-K partials (4 MB)
//   tkt @ 5M  : int tickets
#define OFF_W2T (1024 * 1024)
#define OFF_P1  (2 * 1024 * 1024)
#define OFF_P2  (4 * 1024 * 1024)
#define OFF_TKT (5 * 1024 * 1024)

__global__ __launch_bounds__(256) void zero_kernel(float4* __restrict__ w,
                                                   int* __restrict__ tkt) {
    const int i = blockIdx.x * 256 + threadIdx.x;
    w[i] = make_float4(0.f, 0.f, 0.f, 0.f);           // 2048 blocks * 4KB = 8 MB
    if (blockIdx.x == 0 && threadIdx.x < 64) tkt[threadIdx.x] = 0;
}

// Flat edge-parallel scatter into pre-zeroed dense W. (src,dst) unique -> plain stores.
__global__ __launch_bounds__(256) void scatter_kernel(
        const int* __restrict__ src1, const int* __restrict__ dst1,
        const float* __restrict__ w1, int E1,
        const int* __restrict__ src2, const int* __restrict__ dst2,
        const float* __restrict__ w2, int E2,
        float* __restrict__ W1T, float* __restrict__ W2T) {
    const int e = blockIdx.x * 256 + threadIdx.x;
    if (e < E1) {
        W1T[src1[e] * N_ASS + (dst1[e] - ASS0)] = w1[e];
    } else if (e - E1 < E2) {
        const int i = e - E1;
        const int d = dst2[i];
        if (d >= OUT0)   // only edges into output nodes affect the result
            W2T[(src2[i] - ASS0) * OUT_F + (d - OUT0)] = w2[i];
    }
}

// Split-K NN GEMM: P[z][BATCH][N_] = A[BATCH][lda](cols z*128..) @ B[k][N_].
// BM=BN=64, BK=64, 2 K-iters (KCHUNK=128), 256 threads, 4x4 micro-tile,
// register-prefetched. DUAL_A: A := A + A(+BATCH*lda) summed on load (consumes
// gemm1's 2 partials with no extra pass). FUSE_OUT: last-arriving block per
// (m,n) tile sums all NZ partials in fixed z-order and writes `out`.
template<int N_, int NZ, bool DUAL_A, bool FUSE_OUT>
__global__ __launch_bounds__(256) void gemm64(const float* __restrict__ A, int lda,
                                              const float* __restrict__ B,
                                              float* __restrict__ P,
                                              float* __restrict__ out,
                                              int* __restrict__ tickets) {
    __shared__ __align__(16) float As[64][68];   // [m][k], 272B row: write 2-way max
    __shared__ __align__(16) float Bs[64][68];   // [k][n]

    const int tid = threadIdx.x;
    const int m0 = blockIdx.x * 64;
    const int n0 = blockIdx.y * 64;
    const int z  = blockIdx.z;
    const int kBeg = z * 128;

    float4 areg[4], breg[4];
    #pragma unroll
    for (int r = 0; r < 4; ++r) {
        const int j = tid + r * 256;
        const float* ap = A + (size_t)(m0 + (j >> 4)) * lda + kBeg + (j & 15) * 4;
        areg[r] = *(const float4*)ap;
        if constexpr (DUAL_A) {
            const float4 a2 = *(const float4*)(ap + (size_t)BATCH * lda);
            areg[r].x += a2.x; areg[r].y += a2.y; areg[r].z += a2.z; areg[r].w += a2.w;
        }
        breg[r] = *(const float4*)(B + (size_t)(kBeg + (j >> 4)) * N_ + n0 + (j & 15) * 4);
    }

    const int ty4 = (tid >> 4) * 4;   // 16 m-groups * 4 rows
    const int tx4 = (tid & 15) * 4;   // 16 n-groups * 4 cols
    float c[4][4] = {};

    #pragma unroll
    for (int it = 0; it < 2; ++it) {
        if (it) __syncthreads();      // previous compute done before LDS overwrite
        #pragma unroll
        for (int r = 0; r < 4; ++r) {
            const int j = tid + r * 256;
            *(float4*)&As[j >> 4][(j & 15) * 4] = areg[r];
            *(float4*)&Bs[j >> 4][(j & 15) * 4] = breg[r];
        }
        __syncthreads();
        if (it == 0) {                // prefetch next K-slab into registers
            const int k0 = kBeg + 64;
            #pragma unroll
            for (int r = 0; r < 4; ++r) {
                const int j = tid + r * 256;
                const float* ap = A + (size_t)(m0 + (j >> 4)) * lda + k0 + (j & 15) * 4;
                areg[r] = *(const float4*)ap;
                if constexpr (DUAL_A) {
                    const float4 a2 = *(const float4*)(ap + (size_t)BATCH * lda);
                    areg[r].x += a2.x; areg[r].y += a2.y; areg[r].z += a2.z; areg[r].w += a2.w;
                }
                breg[r] = *(const float4*)(B + (size_t)(k0 + (j >> 4)) * N_ + n0 + (j & 15) * 4);
            }
        }
        #pragma unroll
        for (int kk = 0; kk < 64; kk += 4) {
            float4 ar[4];
            #pragma unroll
            for (int i = 0; i < 4; ++i) ar[i] = *(const float4*)&As[ty4 + i][kk];
            #pragma unroll
            for (int u = 0; u < 4; ++u) {
                const float4 b = *(const float4*)&Bs[kk + u][tx4];
                #pragma unroll
                for (int i = 0; i < 4; ++i) {
                    const float a = ((const float*)&ar[i])[u];
                    c[i][0] = fmaf(a, b.x, c[i][0]);
                    c[i][1] = fmaf(a, b.y, c[i][1]);
                    c[i][2] = fmaf(a, b.z, c[i][2]);
                    c[i][3] = fmaf(a, b.w, c[i][3]);
                }
            }
        }
    }

    // write this K-chunk's partial
    float* Pz = P + (size_t)z * (BATCH * N_);
    #pragma unroll
    for (int i = 0; i < 4; ++i)
        *(float4*)&Pz[(size_t)(m0 + ty4 + i) * N_ + n0 + tx4] =
            make_float4(c[i][0], c[i][1], c[i][2], c[i][3]);

    if constexpr (FUSE_OUT) {
        // last-arriving block per (m,n) tile reduces all NZ partials (no spinning)
        __threadfence();              // release partial writes (device scope)
        __syncthreads();
        __shared__ int s_last;
        if (tid == 0) {
            const int old = __hip_atomic_fetch_add(
                &tickets[blockIdx.y * gridDim.x + blockIdx.x], 1,
                __ATOMIC_ACQ_REL, __HIP_MEMORY_SCOPE_AGENT);
            s_last = (old == NZ - 1);
        }
        __syncthreads();
        if (s_last) {
            __threadfence();          // acquire: see all blocks' partials
            #pragma unroll
            for (int i = 0; i < 4; ++i) {
                const size_t off = (size_t)(m0 + ty4 + i) * N_ + n0 + tx4;
                float4 s = make_float4(0.f, 0.f, 0.f, 0.f);
                for (int zz = 0; zz < NZ; ++zz) {   // fixed order -> deterministic
                    const float4 p = *(const float4*)&P[(size_t)zz * (BATCH * N_) + off];
                    s.x += p.x; s.y += p.y; s.z += p.z; s.w += p.w;
                }
                *(float4*)&out[off] = s;
            }
        }
    }
}

extern "C" void kernel_launch(void* const* d_in, const int* in_sizes, int n_in,
                              void* d_out, int out_size, void* d_ws, size_t ws_size,
                              hipStream_t stream) {
    const float* x      = (const float*)d_in[0];
    const float* w_in   = (const float*)d_in[1];
    const float* w_ass  = (const float*)d_in[2];
    const int*   in_src = (const int*)d_in[3];
    const int*   in_dst = (const int*)d_in[4];
    const int*   a_src  = (const int*)d_in[5];
    const int*   a_dst  = (const int*)d_in[6];
    const int E1 = in_sizes[3];
    const int E2 = in_sizes[5];

    float* ws  = (float*)d_ws;
    float* W1T = ws;
    float* W2T = ws + OFF_W2T;
    float* P1  = ws + OFF_P1;
    float* P2  = ws + OFF_P2;
    int*   tkt = (int*)(ws + OFF_TKT);
    float* out = (float*)d_out;

    // 1) zero dense weights (8 MB) + tickets
    zero_kernel<<<2048, 256, 0, stream>>>((float4*)d_ws, tkt);

    // 2) scatter both edge lists
    scatter_kernel<<<(E1 + E2 + 255) / 256, 256, 0, stream>>>(
        in_src, in_dst, w_in, E1, a_src, a_dst, w_ass, E2, W1T, W2T);

    // 3) GEMM1: P1[z][128][4096] = x[:, z*128..] @ W1T  (grid 2x64x2 = 256 blocks)
    gemm64<N_ASS, 2, false, false><<<dim3(2, 64, 2), 256, 0, stream>>>(
        x, IN_F, W1T, P1, nullptr, nullptr);

    // 4) GEMM2: P2[z] = (P1[0]+P1[1])[:, z*128..] @ W2T; last block per tile
    //    reduces 32 partials -> out  (grid 2x4x32 = 256 blocks)
    gemm64<OUT_F, SPLITK2, true, true><<<dim3(2, 4, SPLITK2), 256, 0, stream>>>(
        P1, N_ASS, W2T, P2, out, tkt);
}

// Round 7
// 40.740 us; speedup vs baseline: 1.7781x; 1.7781x over previous
//
#include <hip/hip_runtime.h>

// Problem constants (fixed by the reference's setup_inputs, seed 0)
#define IN_F   256
#define N_ASS  4096
#define OUT_F  256
#define BATCH  128
#define ASS0   256      // first associative node index
#define OUT0   4352     // first output node index
#define SPLITK2 32      // gemm2 split-K (K=4096 -> 32 chunks of 128)

// ws layout (float offsets):
//   W1T @ 0   : [IN_F=256][N_ASS=4096]   input->assoc, src-major (4 MB)
//   W2T @ 1M  : [N_ASS=4096][OUT_F=256]  assoc->output, src-major (4 MB)
//   P1  @ 2M  : [2][BATCH=128][N_ASS]    gemm1 split-K partials (4 MB)
//   P2  @ 4M  : [32][BATCH][OUT_F]       gemm2 split-K partials (4 MB)
#define OFF_W2T (1024 * 1024)
#define OFF_P1  (2 * 1024 * 1024)
#define OFF_P2  (4 * 1024 * 1024)

__global__ __launch_bounds__(256) void zero_kernel(float4* __restrict__ w) {
    const int i = blockIdx.x * 256 + threadIdx.x;
    w[i] = make_float4(0.f, 0.f, 0.f, 0.f);           // 2048 blocks * 4KB = 8 MB
}

// Flat edge-parallel scatter into pre-zeroed dense W. (src,dst) unique -> plain stores.
__global__ __launch_bounds__(256) void scatter_kernel(
        const int* __restrict__ src1, const int* __restrict__ dst1,
        const float* __restrict__ w1, int E1,
        const int* __restrict__ src2, const int* __restrict__ dst2,
        const float* __restrict__ w2, int E2,
        float* __restrict__ W1T, float* __restrict__ W2T) {
    const int e = blockIdx.x * 256 + threadIdx.x;
    if (e < E1) {
        W1T[src1[e] * N_ASS + (dst1[e] - ASS0)] = w1[e];
    } else if (e - E1 < E2) {
        const int i = e - E1;
        const int d = dst2[i];
        if (d >= OUT0)   // only edges into output nodes affect the result
            W2T[(src2[i] - ASS0) * OUT_F + (d - OUT0)] = w2[i];
    }
}

// Split-K NN GEMM: P[z][BATCH][N_] = A[BATCH][lda](cols z*128..) @ B[k][N_].
// BM=BN=64, BK=64, 2 K-iters (KCHUNK=128), 256 threads, 4x4 micro-tile,
// register-prefetched. DUAL_A: A := A + A(+BATCH*lda) summed on load (consumes
// gemm1's 2 partials with no extra pass). No fences, no atomics, no tail.
template<int N_, bool DUAL_A>
__global__ __launch_bounds__(256) void gemm64(const float* __restrict__ A, int lda,
                                              const float* __restrict__ B,
                                              float* __restrict__ P) {
    __shared__ __align__(16) float As[64][68];   // [m][k]
    __shared__ __align__(16) float Bs[64][68];   // [k][n]

    const int tid = threadIdx.x;
    const int m0 = blockIdx.x * 64;
    const int n0 = blockIdx.y * 64;
    const int z  = blockIdx.z;
    const int kBeg = z * 128;

    float4 areg[4], breg[4];
    #pragma unroll
    for (int r = 0; r < 4; ++r) {
        const int j = tid + r * 256;
        const float* ap = A + (size_t)(m0 + (j >> 4)) * lda + kBeg + (j & 15) * 4;
        areg[r] = *(const float4*)ap;
        if constexpr (DUAL_A) {
            const float4 a2 = *(const float4*)(ap + (size_t)BATCH * lda);
            areg[r].x += a2.x; areg[r].y += a2.y; areg[r].z += a2.z; areg[r].w += a2.w;
        }
        breg[r] = *(const float4*)(B + (size_t)(kBeg + (j >> 4)) * N_ + n0 + (j & 15) * 4);
    }

    const int ty4 = (tid >> 4) * 4;
    const int tx4 = (tid & 15) * 4;
    float c[4][4] = {};

    #pragma unroll
    for (int it = 0; it < 2; ++it) {
        if (it) __syncthreads();      // previous compute done before LDS overwrite
        #pragma unroll
        for (int r = 0; r < 4; ++r) {
            const int j = tid + r * 256;
            *(float4*)&As[j >> 4][(j & 15) * 4] = areg[r];
            *(float4*)&Bs[j >> 4][(j & 15) * 4] = breg[r];
        }
        __syncthreads();
        if (it == 0) {                // prefetch next K-slab into registers
            const int k0 = kBeg + 64;
            #pragma unroll
            for (int r = 0; r < 4; ++r) {
                const int j = tid + r * 256;
                const float* ap = A + (size_t)(m0 + (j >> 4)) * lda + k0 + (j & 15) * 4;
                areg[r] = *(const float4*)ap;
                if constexpr (DUAL_A) {
                    const float4 a2 = *(const float4*)(ap + (size_t)BATCH * lda);
                    areg[r].x += a2.x; areg[r].y += a2.y; areg[r].z += a2.z; areg[r].w += a2.w;
                }
                breg[r] = *(const float4*)(B + (size_t)(k0 + (j >> 4)) * N_ + n0 + (j & 15) * 4);
            }
        }
        #pragma unroll
        for (int kk = 0; kk < 64; kk += 4) {
            float4 ar[4];
            #pragma unroll
            for (int i = 0; i < 4; ++i) ar[i] = *(const float4*)&As[ty4 + i][kk];
            #pragma unroll
            for (int u = 0; u < 4; ++u) {
                const float4 b = *(const float4*)&Bs[kk + u][tx4];
                #pragma unroll
                for (int i = 0; i < 4; ++i) {
                    const float a = ((const float*)&ar[i])[u];
                    c[i][0] = fmaf(a, b.x, c[i][0]);
                    c[i][1] = fmaf(a, b.y, c[i][1]);
                    c[i][2] = fmaf(a, b.z, c[i][2]);
                    c[i][3] = fmaf(a, b.w, c[i][3]);
                }
            }
        }
    }

    float* Pz = P + (size_t)z * (BATCH * N_);
    #pragma unroll
    for (int i = 0; i < 4; ++i)
        *(float4*)&Pz[(size_t)(m0 + ty4 + i) * N_ + n0 + tx4] =
            make_float4(c[i][0], c[i][1], c[i][2], c[i][3]);
}

// out = sum_z P2[z]; 8192 threads, one float4 each, 32 independent loads.
__global__ __launch_bounds__(128) void reduce_kernel(const float4* __restrict__ P4,
                                                     float4* __restrict__ out4) {
    const int g = blockIdx.x * 128 + threadIdx.x;   // 0..8191
    float4 s = make_float4(0.f, 0.f, 0.f, 0.f);
    #pragma unroll
    for (int z = 0; z < SPLITK2; ++z) {             // fixed order -> deterministic
        const float4 p = P4[(size_t)z * 8192 + g];
        s.x += p.x; s.y += p.y; s.z += p.z; s.w += p.w;
    }
    out4[g] = s;
}

extern "C" void kernel_launch(void* const* d_in, const int* in_sizes, int n_in,
                              void* d_out, int out_size, void* d_ws, size_t ws_size,
                              hipStream_t stream) {
    const float* x      = (const float*)d_in[0];
    const float* w_in   = (const float*)d_in[1];
    const float* w_ass  = (const float*)d_in[2];
    const int*   in_src = (const int*)d_in[3];
    const int*   in_dst = (const int*)d_in[4];
    const int*   a_src  = (const int*)d_in[5];
    const int*   a_dst  = (const int*)d_in[6];
    const int E1 = in_sizes[3];
    const int E2 = in_sizes[5];

    float* ws  = (float*)d_ws;
    float* W1T = ws;
    float* W2T = ws + OFF_W2T;
    float* P1  = ws + OFF_P1;
    float* P2  = ws + OFF_P2;
    float* out = (float*)d_out;

    // 1) zero dense weights (8 MB)
    zero_kernel<<<2048, 256, 0, stream>>>((float4*)d_ws);

    // 2) scatter both edge lists
    scatter_kernel<<<(E1 + E2 + 255) / 256, 256, 0, stream>>>(
        in_src, in_dst, w_in, E1, a_src, a_dst, w_ass, E2, W1T, W2T);

    // 3) GEMM1: P1[z][128][4096] = x[:, z*128..] @ W1T  (grid 2x64x2 = 256 blocks)
    gemm64<N_ASS, false><<<dim3(2, 64, 2), 256, 0, stream>>>(x, IN_F, W1T, P1);

    // 4) GEMM2: P2[z] = (P1[0]+P1[1])[:, z*128..] @ W2T  (grid 2x4x32 = 256 blocks)
    gemm64<OUT_F, true><<<dim3(2, 4, SPLITK2), 256, 0, stream>>>(P1, N_ASS, W2T, P2);

    // 5) out = sum of split-K partials (wide, vectorized, fixed order)
    reduce_kernel<<<64, 128, 0, stream>>>((const float4*)P2, (float4*)d_out);
}